// Round 12
// baseline (101.002 us; speedup 1.0000x reference)
//
#include <hip/hip_runtime.h>
#include <hip/hip_bf16.h>

// DualMem fast_get_image_pred:
//   logits[b,c] = 100 * (Σ_m w_m sim_m) / sqrt(Σ_{i,j} w_i w_j G[c,i,j])
//
// Lesson ledger (12 rounds):
//  - Spill triggers on this compiler: (a) allocator starvation from
//    launch_bounds 2nd arg / non-256 blocks / >=48KB LDS (64-88 VGPR);
//    (b) local arrays passed by pointer to helpers -> scratch (R9/R10
//    gram: 140MB scratch regardless of batch width). Keep live sets small,
//    no escaped arrays, plain __launch_bounds__(256), no big LDS.
//  - R4: loads whose address ignores lane bits are wave-duplicated through
//    L1 (16x dup). Keep addresses lane-distinct.
//  - R11: fp32-VALU sim pays 528 shuffle ops vs 704 FMAs and re-fetches
//    mem 2x (sibling blocks 1000 ids apart). => MFMA sim: one block per
//    class (mem fetched once), no reduction needed (C layout IS sim[b][m]),
//    bf16 error ~1e-4 on unit-norm rows (threshold 0.299).
//
// Structure:
//   K1 sim:  grid(1000); 4 waves; wave w computes 16b x 16m (m padded) via
//            32x mfma_f32_16x16x32_bf16 over K=1024. Zero LDS, zero shuffles.
//   K2 gram: grid(1000,17); one pair per wave, no arrays (R11-proven).
//   K3 finish: grid(250); trivial.

constexpr int Bn = 64;     // batch
constexpr int Cn = 1000;   // classes
constexpr int Mn = 11;     // memories per class
constexpr int Dn = 1024;   // feature dim
constexpr int NP = 66;     // Mn*(Mn+1)/2 unique Gram pairs
constexpr float BETA = 5.5f;

// p-th pair (i<=j) of the upper-triangular 11x11 Gram (compile-time p only!)
constexpr int pairI(int p) {
    int i = 0;
    while (p >= Mn - i) { p -= Mn - i; ++i; }
    return i;
}
constexpr int pairJ(int p) {
    int i = 0;
    while (p >= Mn - i) { p -= Mn - i; ++i; }
    return i + p;
}

typedef __attribute__((ext_vector_type(8))) short bf16x8;
typedef __attribute__((ext_vector_type(4))) float f32x4;

__device__ inline short f2bf(float x) {
    union { __hip_bfloat16 h; short s; } u;
    u.h = __float2bfloat16(x);
    return u.s;
}

__device__ inline bf16x8 pack_bf16x8(const float4 a, const float4 b) {
    bf16x8 r;
    r[0] = f2bf(a.x); r[1] = f2bf(a.y); r[2] = f2bf(a.z); r[3] = f2bf(a.w);
    r[4] = f2bf(b.x); r[5] = f2bf(b.y); r[6] = f2bf(b.z); r[7] = f2bf(b.w);
    return r;
}

// ---------------- K1: sim[c][b][m] via MFMA ----------------
__global__ __launch_bounds__(256) void sim_kernel(
    const float* __restrict__ img, const float* __restrict__ mem,
    float* __restrict__ sim) {
    const int c  = blockIdx.x;
    const int w  = threadIdx.x >> 6;   // wave: b-tile (16 rows)
    const int l  = threadIdx.x & 63;
    const int rw = l & 15;             // A-row (b_local) / B-col (m)
    const int kb = (l >> 4) * 8;       // per-lane k-offset within a K=32 step

    // A: img[w*16 + rw][k], 8 contiguous f32 per lane per step
    const float* ipA = img + (w * 16 + rw) * Dn + kb;
    // B: mem[c][rw][k]; pad rows 11..15 alias row 0 (masked at C-write)
    const int mrow = (rw < Mn) ? rw : 0;
    const float* ipB = mem + (size_t)c * (Mn * Dn) + mrow * Dn + kb;

    f32x4 acc = {0.f, 0.f, 0.f, 0.f};
    for (int kk = 0; kk < Dn / 32; ++kk) {   // 32 K-steps
        const int k0 = 32 * kk;
        const float4 a0 = *reinterpret_cast<const float4*>(ipA + k0);
        const float4 a1 = *reinterpret_cast<const float4*>(ipA + k0 + 4);
        const float4 b0 = *reinterpret_cast<const float4*>(ipB + k0);
        const float4 b1 = *reinterpret_cast<const float4*>(ipB + k0 + 4);
        const bf16x8 af = pack_bf16x8(a0, a1);
        const bf16x8 bf = pack_bf16x8(b0, b1);
        acc = __builtin_amdgcn_mfma_f32_16x16x32_bf16(af, bf, acc, 0, 0, 0);
    }

    // C layout: col = l&15 (m), row = (l>>4)*4 + reg (b_local)  [m89-verified]
    const int mcol = l & 15;
    if (mcol < Mn) {
        const int br = w * 16 + (l >> 4) * 4;
        float* o = sim + (size_t)c * (Bn * Mn) + br * Mn + mcol;
        o[0 * Mn] = acc[0];
        o[1 * Mn] = acc[1];
        o[2 * Mn] = acc[2];
        o[3 * Mn] = acc[3];
    }
}

// ---------------- K2: gram[c][p] — one pair per wave, no arrays ----------------
__global__ __launch_bounds__(256) void gram_kernel(
    const float* __restrict__ mem, float* __restrict__ gram) {
    const int c    = blockIdx.x;
    const int w    = threadIdx.x >> 6;        // wave 0..3
    const int l    = threadIdx.x & 63;        // lane: d = 4*l + 256*k + {0..3}
    const int pidx = blockIdx.y * 4 + w;      // pair index 0..67
    if (pidx >= NP) return;                   // wave-uniform exit (slots 66,67)

    // decode pair (i<=j) — wave-uniform scalar loop, ~10 ops
    int i = 0, p = pidx;
    while (p >= Mn - i) { p -= Mn - i; ++i; }
    const int j = i + p;

    const float* ri = mem + (size_t)c * (Mn * Dn) + i * Dn + 4 * l;
    const float* rj = mem + (size_t)c * (Mn * Dn) + j * Dn + 4 * l;

    float acc = 0.f;
#pragma unroll
    for (int k = 0; k < 4; ++k) {
        const float4 a = *reinterpret_cast<const float4*>(ri + 256 * k);
        const float4 b = *reinterpret_cast<const float4*>(rj + 256 * k);
        acc = fmaf(a.x, b.x, acc);
        acc = fmaf(a.y, b.y, acc);
        acc = fmaf(a.z, b.z, acc);
        acc = fmaf(a.w, b.w, acc);
    }
    acc += __shfl_xor(acc, 1, 64);
    acc += __shfl_xor(acc, 2, 64);
    acc += __shfl_xor(acc, 4, 64);
    acc += __shfl_xor(acc, 8, 64);
    acc += __shfl_xor(acc, 16, 64);
    acc += __shfl_xor(acc, 32, 64);
    if (l == 0) gram[c * NP + pidx] = acc;
}

// ---------------- K3: logits (unchanged) ----------------
__global__ __launch_bounds__(256) void finish_kernel(
    const float* __restrict__ sim, const float* __restrict__ gram,
    float* __restrict__ out) {
    const int b = threadIdx.x & 63;
    const int c = blockIdx.x * 4 + (threadIdx.x >> 6);

    const float* sp = sim + (size_t)c * (Bn * Mn) + b * Mn;
    const float* gp = gram + c * NP;

    float w[Mn];
    float numer = 0.f;
#pragma unroll
    for (int m = 0; m < Mn; ++m) {
        const float s = sp[m];
        w[m]  = __expf(BETA * (s - 1.f));
        numer = fmaf(w[m], s, numer);
    }
    float den2 = 0.f;
#pragma unroll
    for (int p = 0; p < NP; ++p) {
        const float t = w[pairI(p)] * w[pairJ(p)] * gp[p];
        den2 += (pairI(p) == pairJ(p)) ? t : (2.f * t);
    }
    out[b * Cn + c] = 100.f * numer / sqrtf(den2);
}

extern "C" void kernel_launch(void* const* d_in, const int* in_sizes, int n_in,
                              void* d_out, int out_size, void* d_ws, size_t ws_size,
                              hipStream_t stream) {
    const float* img = (const float*)d_in[0];  // [64][1024] f32
    const float* mem = (const float*)d_in[1];  // [1000][11][1024] f32
    float* out = (float*)d_out;                // [64][1000] f32
    (void)in_sizes; (void)n_in; (void)out_size; (void)ws_size;

    float* ws_sim  = (float*)d_ws;             // [1000][64][11]
    float* ws_gram = ws_sim + Cn * Bn * Mn;    // [1000][66]

    sim_kernel<<<dim3(Cn), dim3(256), 0, stream>>>(img, mem, ws_sim);
    gram_kernel<<<dim3(Cn, (NP + 3) / 4), dim3(256), 0, stream>>>(mem, ws_gram);
    finish_kernel<<<dim3(Cn / 4), dim3(256), 0, stream>>>(ws_sim, ws_gram, out);
}

// Round 13
// 69.097 us; speedup vs baseline: 1.4617x; 1.4617x over previous
//
#include <hip/hip_runtime.h>
#include <hip/hip_bf16.h>

// DualMem fast_get_image_pred:
//   logits[b,c] = 100 * (Σ_m w_m sim_m) / sqrt(Σ_{i,j} w_i w_j G[c,i,j])
//
// Lesson ledger (13 rounds):
//  - Spill triggers: (a) launch_bounds 2nd arg / non-256 blocks / >=48KB LDS
//    starve the allocator (64-88 VGPR); (b) local arrays passed to helpers
//    go to scratch (R9/R10). Keep live sets bounded, no escaped arrays,
//    plain __launch_bounds__(256), no big LDS.
//  - R12 (inverse problem): VGPR 24 = compiler kept the MFMA K-loop serial;
//    load->cvt->mfma chain latency-bound at 1.3% MfmaUtil. LDS-free kernels
//    have register headroom: SPEND it with #pragma unroll 4 (~16 loads in
//    flight, ~80 live, still under the ~128 no-spill line).
//  - R4: lane-duplicated addresses are wave-duplicated through L1.
//  - R11: escaped-array gram spilled 140MB; one-pair-per-wave fixed it; now
//    replaced by MFMA gram: G = mem.mem^T is one MFMA chain with A=B
//    (transpose-immune since G symmetric), 1 wave/class.
//
// Structure:
//   K1 sim:  grid(1000); 4 waves; wave w: 16b x 16m tile, 32 MFMA over K,
//            unroll 4. Zero LDS, zero shuffles.
//   K2 gram: grid(250); 4 waves; wave w: class 4*bid+w, 32 MFMA, af==bf.
//            Writes full 11x11.
//   K3 finish: grid(250); plain double sum over G[11][11].

constexpr int Bn = 64;     // batch
constexpr int Cn = 1000;   // classes
constexpr int Mn = 11;     // memories per class
constexpr int Dn = 1024;   // feature dim
constexpr float BETA = 5.5f;

typedef __attribute__((ext_vector_type(8))) short bf16x8;
typedef __attribute__((ext_vector_type(4))) float f32x4;

__device__ inline short f2bf(float x) {
    union { __hip_bfloat16 h; short s; } u;
    u.h = __float2bfloat16(x);
    return u.s;
}

__device__ inline bf16x8 pack_bf16x8(const float4 a, const float4 b) {
    bf16x8 r;
    r[0] = f2bf(a.x); r[1] = f2bf(a.y); r[2] = f2bf(a.z); r[3] = f2bf(a.w);
    r[4] = f2bf(b.x); r[5] = f2bf(b.y); r[6] = f2bf(b.z); r[7] = f2bf(b.w);
    return r;
}

// ---------------- K1: sim[c][b][m] via MFMA ----------------
__global__ __launch_bounds__(256) void sim_kernel(
    const float* __restrict__ img, const float* __restrict__ mem,
    float* __restrict__ sim) {
    const int c  = blockIdx.x;
    const int w  = threadIdx.x >> 6;   // wave: b-tile (16 rows)
    const int l  = threadIdx.x & 63;
    const int rw = l & 15;             // A-row (b_local) / B-row (m)
    const int kb = (l >> 4) * 8;       // per-lane k-offset within a K=32 step

    // A: img[w*16 + rw][k], 8 contiguous f32 per lane per step
    const float* ipA = img + (w * 16 + rw) * Dn + kb;
    // B: mem[c][rw][k]; pad rows 11..15 alias row 0 (masked at C-write)
    const int mrow = (rw < Mn) ? rw : 0;
    const float* ipB = mem + (size_t)c * (Mn * Dn) + mrow * Dn + kb;

    f32x4 acc = {0.f, 0.f, 0.f, 0.f};
#pragma unroll 4
    for (int kk = 0; kk < Dn / 32; ++kk) {   // 32 K-steps, 4-deep load pipeline
        const int k0 = 32 * kk;
        const float4 a0 = *reinterpret_cast<const float4*>(ipA + k0);
        const float4 a1 = *reinterpret_cast<const float4*>(ipA + k0 + 4);
        const float4 b0 = *reinterpret_cast<const float4*>(ipB + k0);
        const float4 b1 = *reinterpret_cast<const float4*>(ipB + k0 + 4);
        const bf16x8 af = pack_bf16x8(a0, a1);
        const bf16x8 bf = pack_bf16x8(b0, b1);
        acc = __builtin_amdgcn_mfma_f32_16x16x32_bf16(af, bf, acc, 0, 0, 0);
    }

    // C layout: col = l&15 (m), row = (l>>4)*4 + reg (b_local)
    const int mcol = l & 15;
    if (mcol < Mn) {
        const int br = w * 16 + (l >> 4) * 4;
        float* o = sim + (size_t)c * (Bn * Mn) + br * Mn + mcol;
        o[0 * Mn] = acc[0];
        o[1 * Mn] = acc[1];
        o[2 * Mn] = acc[2];
        o[3 * Mn] = acc[3];
    }
}

// ---------------- K2: gram2[c][i][j] via MFMA (A==B) ----------------
__global__ __launch_bounds__(256) void gram_kernel(
    const float* __restrict__ mem, float* __restrict__ gram2) {
    const int c  = blockIdx.x * 4 + (threadIdx.x >> 6);  // wave -> class
    const int l  = threadIdx.x & 63;
    const int rw = l & 15;
    const int kb = (l >> 4) * 8;

    const int mrow = (rw < Mn) ? rw : 0;   // pad rows alias row 0
    const float* ip = mem + (size_t)c * (Mn * Dn) + mrow * Dn + kb;

    f32x4 acc = {0.f, 0.f, 0.f, 0.f};
#pragma unroll 4
    for (int kk = 0; kk < Dn / 32; ++kk) {
        const int k0 = 32 * kk;
        const float4 a0 = *reinterpret_cast<const float4*>(ip + k0);
        const float4 a1 = *reinterpret_cast<const float4*>(ip + k0 + 4);
        const bf16x8 af = pack_bf16x8(a0, a1);
        acc = __builtin_amdgcn_mfma_f32_16x16x32_bf16(af, af, acc, 0, 0, 0);
    }

    // C[i][j] = mem_i . mem_j (symmetric -> layout-swap immune)
    const int col = l & 15;
    const int r0  = (l >> 4) * 4;
    if (col < Mn) {
        float* o = gram2 + (size_t)c * (Mn * Mn) + col;
        if (r0 + 0 < Mn) o[(r0 + 0) * Mn] = acc[0];
        if (r0 + 1 < Mn) o[(r0 + 1) * Mn] = acc[1];
        if (r0 + 2 < Mn) o[(r0 + 2) * Mn] = acc[2];
        if (r0 + 3 < Mn) o[(r0 + 3) * Mn] = acc[3];
    }
}

// ---------------- K3: logits ----------------
__global__ __launch_bounds__(256) void finish_kernel(
    const float* __restrict__ sim, const float* __restrict__ gram2,
    float* __restrict__ out) {
    const int b = threadIdx.x & 63;
    const int c = blockIdx.x * 4 + (threadIdx.x >> 6);

    const float* sp = sim + (size_t)c * (Bn * Mn) + b * Mn;
    const float* gp = gram2 + (size_t)c * (Mn * Mn);

    float w[Mn];
    float numer = 0.f;
#pragma unroll
    for (int m = 0; m < Mn; ++m) {
        const float s = sp[m];
        w[m]  = __expf(BETA * (s - 1.f));
        numer = fmaf(w[m], s, numer);
    }
    float den2 = 0.f;
#pragma unroll
    for (int i = 0; i < Mn; ++i) {
        float row = 0.f;
#pragma unroll
        for (int j = 0; j < Mn; ++j) row = fmaf(w[j], gp[i * Mn + j], row);
        den2 = fmaf(w[i], row, den2);
    }
    out[b * Cn + c] = 100.f * numer / sqrtf(den2);
}

extern "C" void kernel_launch(void* const* d_in, const int* in_sizes, int n_in,
                              void* d_out, int out_size, void* d_ws, size_t ws_size,
                              hipStream_t stream) {
    const float* img = (const float*)d_in[0];  // [64][1024] f32
    const float* mem = (const float*)d_in[1];  // [1000][11][1024] f32
    float* out = (float*)d_out;                // [64][1000] f32
    (void)in_sizes; (void)n_in; (void)out_size; (void)ws_size;

    float* ws_sim   = (float*)d_ws;            // [1000][64][11]
    float* ws_gram2 = ws_sim + Cn * Bn * Mn;   // [1000][11][11]

    sim_kernel<<<dim3(Cn), dim3(256), 0, stream>>>(img, mem, ws_sim);
    gram_kernel<<<dim3(Cn / 4), dim3(256), 0, stream>>>(mem, ws_gram2);
    finish_kernel<<<dim3(Cn / 4), dim3(256), 0, stream>>>(ws_sim, ws_gram2, out);
}

// Round 15
// 68.905 us; speedup vs baseline: 1.4658x; 1.0028x over previous
//
#include <hip/hip_runtime.h>
#include <hip/hip_bf16.h>

// DualMem fast_get_image_pred:
//   logits[b,c] = 100 * (Σ_m w_m sim_m) / sqrt(Σ_{i,j} w_i w_j G[c,i,j])
//
// Lesson ledger (15 rounds):
//  - Spill triggers: (a) launch_bounds 2nd arg / non-256 blocks / >=48KB LDS
//    starve the allocator; (b) local arrays passed to helpers -> scratch.
//  - R12/R13: serial load->cvt->mfma K-loop is latency-bound; '#pragma
//    unroll N' does NOT pipeline (compiler re-serializes, VGPR 16). Force
//    pipelining with DATA DEPENDENCE: slot rotation where MFMA(k) reads
//    registers the loads of k+4 overwrite. Static indices, no helpers.
//  - R14 BUG: 4 rounds x 4 slots covered only K=512 of 1024 (absmax 10.5).
//    32 K-steps / 4 slots = 8 ROUNDS. Preload 0..3; round r MFMAs steps
//    4r..4r+3 and reloads steps 4r+4..4r+7 (guard r<7).
//  - R4: lane-duplicated addresses are wave-duplicated through L1.
//  - MFMA C-layout col=lane&15, row=(lane>>4)*4+reg (verified R12/R13).
//
// Structure:
//   K1 sim:  grid(1000); 4 waves; wave w: 16b x 16m tile; 32 K-steps as
//            8-round x 4-slot software pipeline. Zero LDS, zero shuffles.
//   K2 gram: grid(250); 4 waves; wave w: class 4*bid+w, MFMA with A==B.
//   K3 finish: grid(250); plain double sum over G[11][11].

constexpr int Bn = 64;     // batch
constexpr int Cn = 1000;   // classes
constexpr int Mn = 11;     // memories per class
constexpr int Dn = 1024;   // feature dim
constexpr float BETA = 5.5f;

typedef __attribute__((ext_vector_type(8))) short bf16x8;
typedef __attribute__((ext_vector_type(4))) float f32x4;

__device__ inline short f2bf(float x) {
    union { __hip_bfloat16 h; short s; } u;
    u.h = __float2bfloat16(x);
    return u.s;
}

__device__ inline bf16x8 pack_bf16x8(const float4 a, const float4 b) {
    bf16x8 r;
    r[0] = f2bf(a.x); r[1] = f2bf(a.y); r[2] = f2bf(a.z); r[3] = f2bf(a.w);
    r[4] = f2bf(b.x); r[5] = f2bf(b.y); r[6] = f2bf(b.z); r[7] = f2bf(b.w);
    return r;
}

// ---------------- K1: sim[c][b][m] via MFMA, 8-round 4-slot pipeline ----------------
__global__ __launch_bounds__(256) void sim_kernel(
    const float* __restrict__ img, const float* __restrict__ mem,
    float* __restrict__ sim) {
    const int c  = blockIdx.x;
    const int w  = threadIdx.x >> 6;   // wave: b-tile (16 rows)
    const int l  = threadIdx.x & 63;
    const int rw = l & 15;             // A-row (b_local) / B-row (m)
    const int kb = (l >> 4) * 8;       // per-lane k-offset within a K=32 step

    const float* ipA = img + (w * 16 + rw) * Dn + kb;
    const int mrow = (rw < Mn) ? rw : 0;   // pad rows alias row 0
    const float* ipB = mem + (size_t)c * (Mn * Dn) + mrow * Dn + kb;

    // 4 pipeline slots, static-indexed only (fully unrolled loops)
    float4 sa0[4], sa1[4], sb0[4], sb1[4];
#pragma unroll
    for (int s = 0; s < 4; ++s) {
        sa0[s] = *reinterpret_cast<const float4*>(ipA + 32 * s);
        sa1[s] = *reinterpret_cast<const float4*>(ipA + 32 * s + 4);
        sb0[s] = *reinterpret_cast<const float4*>(ipB + 32 * s);
        sb1[s] = *reinterpret_cast<const float4*>(ipB + 32 * s + 4);
    }

    f32x4 acc = {0.f, 0.f, 0.f, 0.f};
#pragma unroll
    for (int r = 0; r < 8; ++r) {          // 8 rounds x 4 slots = 32 K-steps
#pragma unroll
        for (int s = 0; s < 4; ++s) {
            const bf16x8 af = pack_bf16x8(sa0[s], sa1[s]);
            const bf16x8 bf = pack_bf16x8(sb0[s], sb1[s]);
            acc = __builtin_amdgcn_mfma_f32_16x16x32_bf16(af, bf, acc, 0, 0, 0);
            if (r < 7) {  // reload this slot for step 4r+s+4 (WAR pins order)
                const int kn = 32 * (4 * r + s + 4);
                sa0[s] = *reinterpret_cast<const float4*>(ipA + kn);
                sa1[s] = *reinterpret_cast<const float4*>(ipA + kn + 4);
                sb0[s] = *reinterpret_cast<const float4*>(ipB + kn);
                sb1[s] = *reinterpret_cast<const float4*>(ipB + kn + 4);
            }
        }
    }

    // C layout: col = l&15 (m), row = (l>>4)*4 + reg (b_local)
    const int mcol = l & 15;
    if (mcol < Mn) {
        const int br = w * 16 + (l >> 4) * 4;
        float* o = sim + (size_t)c * (Bn * Mn) + br * Mn + mcol;
        o[0 * Mn] = acc[0];
        o[1 * Mn] = acc[1];
        o[2 * Mn] = acc[2];
        o[3 * Mn] = acc[3];
    }
}

// ---------------- K2: gram2[c][i][j] via MFMA (A==B, unchanged R13) ----------------
__global__ __launch_bounds__(256) void gram_kernel(
    const float* __restrict__ mem, float* __restrict__ gram2) {
    const int c  = blockIdx.x * 4 + (threadIdx.x >> 6);  // wave -> class
    const int l  = threadIdx.x & 63;
    const int rw = l & 15;
    const int kb = (l >> 4) * 8;

    const int mrow = (rw < Mn) ? rw : 0;   // pad rows alias row 0
    const float* ip = mem + (size_t)c * (Mn * Dn) + mrow * Dn + kb;

    f32x4 acc = {0.f, 0.f, 0.f, 0.f};
#pragma unroll 4
    for (int kk = 0; kk < Dn / 32; ++kk) {
        const int k0 = 32 * kk;
        const float4 a0 = *reinterpret_cast<const float4*>(ip + k0);
        const float4 a1 = *reinterpret_cast<const float4*>(ip + k0 + 4);
        const bf16x8 af = pack_bf16x8(a0, a1);
        acc = __builtin_amdgcn_mfma_f32_16x16x32_bf16(af, af, acc, 0, 0, 0);
    }

    // C[i][j] = mem_i . mem_j (symmetric -> layout-swap immune)
    const int col = l & 15;
    const int r0  = (l >> 4) * 4;
    if (col < Mn) {
        float* o = gram2 + (size_t)c * (Mn * Mn) + col;
        if (r0 + 0 < Mn) o[(r0 + 0) * Mn] = acc[0];
        if (r0 + 1 < Mn) o[(r0 + 1) * Mn] = acc[1];
        if (r0 + 2 < Mn) o[(r0 + 2) * Mn] = acc[2];
        if (r0 + 3 < Mn) o[(r0 + 3) * Mn] = acc[3];
    }
}

// ---------------- K3: logits (unchanged) ----------------
__global__ __launch_bounds__(256) void finish_kernel(
    const float* __restrict__ sim, const float* __restrict__ gram2,
    float* __restrict__ out) {
    const int b = threadIdx.x & 63;
    const int c = blockIdx.x * 4 + (threadIdx.x >> 6);

    const float* sp = sim + (size_t)c * (Bn * Mn) + b * Mn;
    const float* gp = gram2 + (size_t)c * (Mn * Mn);

    float w[Mn];
    float numer = 0.f;
#pragma unroll
    for (int m = 0; m < Mn; ++m) {
        const float s = sp[m];
        w[m]  = __expf(BETA * (s - 1.f));
        numer = fmaf(w[m], s, numer);
    }
    float den2 = 0.f;
#pragma unroll
    for (int i = 0; i < Mn; ++i) {
        float row = 0.f;
#pragma unroll
        for (int j = 0; j < Mn; ++j) row = fmaf(w[j], gp[i * Mn + j], row);
        den2 = fmaf(w[i], row, den2);
    }
    out[b * Cn + c] = 100.f * numer / sqrtf(den2);
}

extern "C" void kernel_launch(void* const* d_in, const int* in_sizes, int n_in,
                              void* d_out, int out_size, void* d_ws, size_t ws_size,
                              hipStream_t stream) {
    const float* img = (const float*)d_in[0];  // [64][1024] f32
    const float* mem = (const float*)d_in[1];  // [1000][11][1024] f32
    float* out = (float*)d_out;                // [64][1000] f32
    (void)in_sizes; (void)n_in; (void)out_size; (void)ws_size;

    float* ws_sim   = (float*)d_ws;            // [1000][64][11]
    float* ws_gram2 = ws_sim + Cn * Bn * Mn;   // [1000][11][11]

    sim_kernel<<<dim3(Cn), dim3(256), 0, stream>>>(img, mem, ws_sim);
    gram_kernel<<<dim3(Cn / 4), dim3(256), 0, stream>>>(mem, ws_gram2);
    finish_kernel<<<dim3(Cn / 4), dim3(256), 0, stream>>>(ws_sim, ws_gram2, out);
}

// Round 16
// 68.791 us; speedup vs baseline: 1.4683x; 1.0017x over previous
//
#include <hip/hip_runtime.h>
#include <hip/hip_bf16.h>

// DualMem fast_get_image_pred:
//   logits[b,c] = 100 * (Σ_m w_m sim_m) / sqrt(Σ_{i,j} w_i w_j G[c,i,j])
//
// Lesson ledger (16 rounds):
//  - Spill triggers: (a) launch_bounds 2nd arg / non-256 blocks / >=48KB LDS
//    starve the allocator; (b) local arrays passed to helpers -> scratch.
//  - R12-R15: a K-loop feeding ONE accumulator is a single serial MFMA
//    chain; the compiler (SSA — WAR tricks don't survive) sinks every load
//    to its use: one outstanding load-group, 56us latency-bound, VGPR 16-32.
//    '#pragma unroll' and hand-rotation DON'T fix it. Fix = MULTIPLE
//    INDEPENDENT ACCUMULATOR CHAINS: chain j owns K-steps {4r+j}; chains
//    have no mutual deps, so their load stalls overlap structurally.
//  - R4: lane-duplicated addresses are wave-duplicated through L1.
//  - MFMA C-layout col=lane&15, row=(lane>>4)*4+reg (verified R12/R13).
//
// Structure:
//   K1 sim:  grid(1000); 4 waves; wave w: 16b x 16m tile; 32 K-steps as
//            8 rounds x 4 independent chains. Zero LDS, zero shuffles.
//   K2 gram: grid(250); 4 waves; wave w: class 4*bid+w, MFMA with A==B.
//   K3 finish: grid(250); plain double sum over G[11][11].

constexpr int Bn = 64;     // batch
constexpr int Cn = 1000;   // classes
constexpr int Mn = 11;     // memories per class
constexpr int Dn = 1024;   // feature dim
constexpr float BETA = 5.5f;

typedef __attribute__((ext_vector_type(8))) short bf16x8;
typedef __attribute__((ext_vector_type(4))) float f32x4;

__device__ inline short f2bf(float x) {
    union { __hip_bfloat16 h; short s; } u;
    u.h = __float2bfloat16(x);
    return u.s;
}

__device__ inline bf16x8 pack_bf16x8(const float4 a, const float4 b) {
    bf16x8 r;
    r[0] = f2bf(a.x); r[1] = f2bf(a.y); r[2] = f2bf(a.z); r[3] = f2bf(a.w);
    r[4] = f2bf(b.x); r[5] = f2bf(b.y); r[6] = f2bf(b.z); r[7] = f2bf(b.w);
    return r;
}

// ---------------- K1: sim[c][b][m] via MFMA, 4 independent chains ----------------
__global__ __launch_bounds__(256) void sim_kernel(
    const float* __restrict__ img, const float* __restrict__ mem,
    float* __restrict__ sim) {
    const int c  = blockIdx.x;
    const int w  = threadIdx.x >> 6;   // wave: b-tile (16 rows)
    const int l  = threadIdx.x & 63;
    const int rw = l & 15;             // A-row (b_local) / B-row (m)
    const int kb = (l >> 4) * 8;       // per-lane k-offset within a K=32 step

    const float* ipA = img + (w * 16 + rw) * Dn + kb;
    const int mrow = (rw < Mn) ? rw : 0;   // pad rows alias row 0
    const float* ipB = mem + (size_t)c * (Mn * Dn) + mrow * Dn + kb;

    // 4 independent accumulator chains; chain j covers K-steps {4r+j}
    f32x4 acc0 = {0.f, 0.f, 0.f, 0.f};
    f32x4 acc1 = {0.f, 0.f, 0.f, 0.f};
    f32x4 acc2 = {0.f, 0.f, 0.f, 0.f};
    f32x4 acc3 = {0.f, 0.f, 0.f, 0.f};

#pragma unroll
    for (int r = 0; r < 8; ++r) {
        const int k0 = 128 * r;   // 4 K-steps of 32 per round
        // all 4 chains' loads first (independent, can all be outstanding)
        const float4 a00 = *reinterpret_cast<const float4*>(ipA + k0);
        const float4 a01 = *reinterpret_cast<const float4*>(ipA + k0 + 4);
        const float4 b00 = *reinterpret_cast<const float4*>(ipB + k0);
        const float4 b01 = *reinterpret_cast<const float4*>(ipB + k0 + 4);
        const float4 a10 = *reinterpret_cast<const float4*>(ipA + k0 + 32);
        const float4 a11 = *reinterpret_cast<const float4*>(ipA + k0 + 36);
        const float4 b10 = *reinterpret_cast<const float4*>(ipB + k0 + 32);
        const float4 b11 = *reinterpret_cast<const float4*>(ipB + k0 + 36);
        const float4 a20 = *reinterpret_cast<const float4*>(ipA + k0 + 64);
        const float4 a21 = *reinterpret_cast<const float4*>(ipA + k0 + 68);
        const float4 b20 = *reinterpret_cast<const float4*>(ipB + k0 + 64);
        const float4 b21 = *reinterpret_cast<const float4*>(ipB + k0 + 68);
        const float4 a30 = *reinterpret_cast<const float4*>(ipA + k0 + 96);
        const float4 a31 = *reinterpret_cast<const float4*>(ipA + k0 + 100);
        const float4 b30 = *reinterpret_cast<const float4*>(ipB + k0 + 96);
        const float4 b31 = *reinterpret_cast<const float4*>(ipB + k0 + 100);
        // then the 4 MFMAs (each depends only on its own chain)
        acc0 = __builtin_amdgcn_mfma_f32_16x16x32_bf16(
            pack_bf16x8(a00, a01), pack_bf16x8(b00, b01), acc0, 0, 0, 0);
        acc1 = __builtin_amdgcn_mfma_f32_16x16x32_bf16(
            pack_bf16x8(a10, a11), pack_bf16x8(b10, b11), acc1, 0, 0, 0);
        acc2 = __builtin_amdgcn_mfma_f32_16x16x32_bf16(
            pack_bf16x8(a20, a21), pack_bf16x8(b20, b21), acc2, 0, 0, 0);
        acc3 = __builtin_amdgcn_mfma_f32_16x16x32_bf16(
            pack_bf16x8(a30, a31), pack_bf16x8(b30, b31), acc3, 0, 0, 0);
    }

    const f32x4 acc01 = acc0 + acc1;
    const f32x4 acc23 = acc2 + acc3;
    const f32x4 acc = acc01 + acc23;

    // C layout: col = l&15 (m), row = (l>>4)*4 + reg (b_local)
    const int mcol = l & 15;
    if (mcol < Mn) {
        const int br = w * 16 + (l >> 4) * 4;
        float* o = sim + (size_t)c * (Bn * Mn) + br * Mn + mcol;
        o[0 * Mn] = acc[0];
        o[1 * Mn] = acc[1];
        o[2 * Mn] = acc[2];
        o[3 * Mn] = acc[3];
    }
}

// ---------------- K2: gram2[c][i][j] via MFMA (A==B, unchanged) ----------------
__global__ __launch_bounds__(256) void gram_kernel(
    const float* __restrict__ mem, float* __restrict__ gram2) {
    const int c  = blockIdx.x * 4 + (threadIdx.x >> 6);  // wave -> class
    const int l  = threadIdx.x & 63;
    const int rw = l & 15;
    const int kb = (l >> 4) * 8;

    const int mrow = (rw < Mn) ? rw : 0;   // pad rows alias row 0
    const float* ip = mem + (size_t)c * (Mn * Dn) + mrow * Dn + kb;

    f32x4 acc = {0.f, 0.f, 0.f, 0.f};
#pragma unroll 4
    for (int kk = 0; kk < Dn / 32; ++kk) {
        const int k0 = 32 * kk;
        const float4 a0 = *reinterpret_cast<const float4*>(ip + k0);
        const float4 a1 = *reinterpret_cast<const float4*>(ip + k0 + 4);
        const bf16x8 af = pack_bf16x8(a0, a1);
        acc = __builtin_amdgcn_mfma_f32_16x16x32_bf16(af, af, acc, 0, 0, 0);
    }

    // C[i][j] = mem_i . mem_j (symmetric -> layout-swap immune)
    const int col = l & 15;
    const int r0  = (l >> 4) * 4;
    if (col < Mn) {
        float* o = gram2 + (size_t)c * (Mn * Mn) + col;
        if (r0 + 0 < Mn) o[(r0 + 0) * Mn] = acc[0];
        if (r0 + 1 < Mn) o[(r0 + 1) * Mn] = acc[1];
        if (r0 + 2 < Mn) o[(r0 + 2) * Mn] = acc[2];
        if (r0 + 3 < Mn) o[(r0 + 3) * Mn] = acc[3];
    }
}

// ---------------- K3: logits (unchanged) ----------------
__global__ __launch_bounds__(256) void finish_kernel(
    const float* __restrict__ sim, const float* __restrict__ gram2,
    float* __restrict__ out) {
    const int b = threadIdx.x & 63;
    const int c = blockIdx.x * 4 + (threadIdx.x >> 6);

    const float* sp = sim + (size_t)c * (Bn * Mn) + b * Mn;
    const float* gp = gram2 + (size_t)c * (Mn * Mn);

    float w[Mn];
    float numer = 0.f;
#pragma unroll
    for (int m = 0; m < Mn; ++m) {
        const float s = sp[m];
        w[m]  = __expf(BETA * (s - 1.f));
        numer = fmaf(w[m], s, numer);
    }
    float den2 = 0.f;
#pragma unroll
    for (int i = 0; i < Mn; ++i) {
        float row = 0.f;
#pragma unroll
        for (int j = 0; j < Mn; ++j) row = fmaf(w[j], gp[i * Mn + j], row);
        den2 = fmaf(w[i], row, den2);
    }
    out[b * Cn + c] = 100.f * numer / sqrtf(den2);
}

extern "C" void kernel_launch(void* const* d_in, const int* in_sizes, int n_in,
                              void* d_out, int out_size, void* d_ws, size_t ws_size,
                              hipStream_t stream) {
    const float* img = (const float*)d_in[0];  // [64][1024] f32
    const float* mem = (const float*)d_in[1];  // [1000][11][1024] f32
    float* out = (float*)d_out;                // [64][1000] f32
    (void)in_sizes; (void)n_in; (void)out_size; (void)ws_size;

    float* ws_sim   = (float*)d_ws;            // [1000][64][11]
    float* ws_gram2 = ws_sim + Cn * Bn * Mn;   // [1000][11][11]

    sim_kernel<<<dim3(Cn), dim3(256), 0, stream>>>(img, mem, ws_sim);
    gram_kernel<<<dim3(Cn / 4), dim3(256), 0, stream>>>(mem, ws_gram2);
    finish_kernel<<<dim3(Cn / 4), dim3(256), 0, stream>>>(ws_sim, ws_gram2, out);
}